// Round 4
// baseline (105.207 us; speedup 1.0000x reference)
//
#include <hip/hip_runtime.h>
#include <stdint.h>

// (B,C,H,W)=(4,128,64,128), R=4, D=9, out channels 81.
// out[b, di*9+dj, h, w] = sum_c src[b,c,h,w] * tgt[b,c,h+di-8,w+dj-8]
// (zero when shifted index leaves [0,H)x[0,W)).
//
// Block = (b, 8x16 spatial tile), ALL channels, ALL 81 offsets.
// grid = 4 * (64/8) * (128/16) = 256 blocks, 320 threads (5 waves).
// Threads: tid<288 -> (di = tid/32, quad = tid%32: r = q>>2, qc = q&3).
// LDS (double-buffered, 8-channel chunks):
//   tgt halo tile [8ch][16r][24w] = 3072 floats, zero-filled OOB
//   src tile      [8ch][ 8r][16w] = 1024 floats
// 2 x 4096 floats = 32 KB.
#define NB 4
#define NC 128
#define NH 64
#define NW 128
#define ND 9
#define NOUT (ND * ND)

#define TH 8
#define TW 16
#define CCH 8                 // channels per chunk
#define NCHUNK (NC / CCH)     // 16
#define TGT_F4 768            // 8*16*6 float4s
#define SRC_F4 256            // 8*8*4 float4s
#define SRC_OFF 3072          // float offset of src region in a buffer
#define BUF_F 4096

__global__ __launch_bounds__(320, 1)
void costvol_kernel(const float* __restrict__ src,
                    const float* __restrict__ tgt,
                    float* __restrict__ out) {
  __shared__ float lds[2][BUF_F];

  const int tid = threadIdx.x;
  const int bid = blockIdx.x;
  const int b  = bid >> 6;
  const int tile = bid & 63;
  const int h0 = (tile >> 3) * TH;   // 0,8,...,56
  const int w0 = (tile & 7) * TW;    // 0,16,...,112

  const int di = tid >> 5;           // 0..9 (9 = idle group)
  const int q  = tid & 31;
  const int r  = q >> 2;             // 0..7
  const int qc = q & 3;              // 0..3

  float acc[ND][4];
#pragma unroll
  for (int dj = 0; dj < ND; ++dj)
#pragma unroll
    for (int k = 0; k < 4; ++k) acc[dj][k] = 0.0f;

  // ---- staging helpers (flat float4 index -> global gather w/ zero fill) ----
  // tgt f4 i in [0,768): ch=i/96, row=(i%96)/6, cq=(i%96)%6
  //   global (y,x) = (h0-8+row, w0-8+4cq); OOB (top rows / left cols) -> 0
  // src f4 i in [0,256): ch=i/32, row=(i%32)/4, cq=i%4 ; always in bounds
  float4 treg[3];
  float4 sreg;

  auto load_regs = [&](int chunk) {
    const int c0 = chunk * CCH;
#pragma unroll
    for (int j = 0; j < 3; ++j) {
      const int i = tid + j * 320;
      if (i < TGT_F4) {
        const int ch = i / 96;
        const int rem = i - ch * 96;
        const int row = rem / 6;
        const int cq = rem - row * 6;
        const int y = h0 - 8 + row;          // <= 63 always
        const int x = w0 - 8 + 4 * cq;       // x+3 <= 127 always
        if (y >= 0 && x >= 0) {
          treg[j] = *(const float4*)(tgt + (size_t)(((b * NC + c0 + ch) * NH + y) * NW + x));
        } else {
          treg[j] = make_float4(0.f, 0.f, 0.f, 0.f);
        }
      }
    }
    if (tid < SRC_F4) {
      const int ch = tid >> 5;
      const int rem = tid & 31;
      const int row = rem >> 2;
      const int cq = rem & 3;
      sreg = *(const float4*)(src + (size_t)(((b * NC + c0 + ch) * NH + h0 + row) * NW + w0 + 4 * cq));
    }
  };

  auto write_lds = [&](int buf) {
#pragma unroll
    for (int j = 0; j < 3; ++j) {
      const int i = tid + j * 320;
      if (i < TGT_F4) *(float4*)&lds[buf][4 * i] = treg[j];
    }
    if (tid < SRC_F4) *(float4*)&lds[buf][SRC_OFF + 4 * tid] = sreg;
  };

  // ---- software-pipelined chunk loop ----
  load_regs(0);
  write_lds(0);
  int cur = 0;

  for (int k = 0; k < NCHUNK; ++k) {
    if (k + 1 < NCHUNK) load_regs(k + 1);   // global loads only, no wait yet
    __syncthreads();                         // buf[cur] ready; buf[cur^1] free

    if (di < ND) {
      const float* sb = &lds[cur][SRC_OFF + r * TW + 4 * qc];
      const float* tb = &lds[cur][(r + di) * 24 + 4 * qc];
#pragma unroll
      for (int ch = 0; ch < CCH; ++ch) {
        const float4 sv = *(const float4*)(sb + ch * (TH * TW));
        const float* tp = tb + ch * 384;
        const float4 t0 = *(const float4*)(tp);
        const float4 t1 = *(const float4*)(tp + 4);
        const float4 t2 = *(const float4*)(tp + 8);
        float t[12];
        t[0] = t0.x; t[1] = t0.y; t[2]  = t0.z; t[3]  = t0.w;
        t[4] = t1.x; t[5] = t1.y; t[6]  = t1.z; t[7]  = t1.w;
        t[8] = t2.x; t[9] = t2.y; t[10] = t2.z; t[11] = t2.w;
#pragma unroll
        for (int dj = 0; dj < ND; ++dj) {
          acc[dj][0] = fmaf(sv.x, t[dj + 0], acc[dj][0]);
          acc[dj][1] = fmaf(sv.y, t[dj + 1], acc[dj][1]);
          acc[dj][2] = fmaf(sv.z, t[dj + 2], acc[dj][2]);
          acc[dj][3] = fmaf(sv.w, t[dj + 3], acc[dj][3]);
        }
      }
    }

    if (k + 1 < NCHUNK) write_lds(cur ^ 1);  // waits on its own globals only
    cur ^= 1;
  }

  // ---- epilogue: 9 float4 stores per compute thread ----
  if (di < ND) {
#pragma unroll
    for (int dj = 0; dj < ND; ++dj) {
      float4 o;
      o.x = acc[dj][0]; o.y = acc[dj][1]; o.z = acc[dj][2]; o.w = acc[dj][3];
      *(float4*)(out + (size_t)(((b * NOUT + di * ND + dj) * NH + h0 + r) * NW + w0 + 4 * qc)) = o;
    }
  }
}

extern "C" void kernel_launch(void* const* d_in, const int* in_sizes, int n_in,
                              void* d_out, int out_size, void* d_ws, size_t ws_size,
                              hipStream_t stream) {
  const float* src = (const float*)d_in[0];
  const float* tgt = (const float*)d_in[1];
  float* out = (float*)d_out;
  costvol_kernel<<<dim3(NB * (NH / TH) * (NW / TW)), dim3(320), 0, stream>>>(src, tgt, out);
}